// Round 9
// baseline (8984.666 us; speedup 1.0000x reference)
//
#include <hip/hip_runtime.h>

static constexpr int KC   = 9;    // kernel bins
static constexpr int CIN  = 32;   // input channels
static constexpr int CA   = 24;   // branch-a out channels
static constexpr int CB   = 8;    // branch-b out channels
static constexpr int COUT = 32;   // CA + CB
static constexpr int WSTR = KC * CIN + 4;   // 292 dwords: packed-W row stride
static constexpr int SPP  = 2 * KC * CIN;   // 576 dwords S per point
static constexpr int REP  = 16;   // ablation repeat count
static constexpr int ABG  = 2048; // ablation grid blocks

// ===========================================================================
// ABLATION KERNELS (diagnostic; results dumped to scratch, overwritten later)
// Round-5 shape: contiguous ~98-edge chunk per half-wave, no LDS limits.
// ===========================================================================

// A1: pure stream — metadata + dependent importance gather + random feats
// row gather. Register accumulate. No atomics, no LDS.
__global__ __launch_bounds__(256) void ab_stream(
    const float* __restrict__ feats, const float* __restrict__ importance,
    const int* __restrict__ nidx, const int* __restrict__ nkidx,
    float* __restrict__ dump, int E)
{
    const int t   = blockIdx.x * 256 + threadIdx.x;
    const int c   = t & 31;
    const int hw  = t >> 5;
    const int nhw = (ABG * 256) >> 5;
    const int per = (E + nhw - 1) / nhw;
    float acc = 0.f;
    for (int r = 0; r < REP; ++r) {
        int e0 = hw * per + ((r * 37) & 63);      // vary start: defeat hoisting
        int e1 = e0 + per; if (e1 > E) e1 = E;
        for (int e = e0; e + 4 <= e1; e += 4) {
            int i0 = nidx[e],     i1 = nidx[e + 1];
            int i2 = nidx[e + 2], i3 = nidx[e + 3];
            int q0 = nkidx[e],     q1 = nkidx[e + 1];
            int q2 = nkidx[e + 2], q3 = nkidx[e + 3];
            float m0 = importance[i0], m1 = importance[i1];
            float m2 = importance[i2], m3 = importance[i3];
            float f0 = feats[(size_t)i0 * CIN + c];
            float f1 = feats[(size_t)i1 * CIN + c];
            float f2 = feats[(size_t)i2 * CIN + c];
            float f3 = feats[(size_t)i3 * CIN + c];
            acc += (f0 + f1) + (f2 + f3) + (m0 + m1) + (m2 + m3)
                 + (float)((q0 + q1) + (q2 + q3));
        }
    }
    dump[t] = acc;
}

// A2: A1 + full LDS S-tile ds_add accumulation (conflict-free banks).
__global__ __launch_bounds__(256) void ab_streamldsS(
    const float* __restrict__ feats, const float* __restrict__ importance,
    const int* __restrict__ nidx, const int* __restrict__ nkidx,
    float* __restrict__ dump, int E)
{
    __shared__ float sS[8][SPP];                 // 18432 B
    const int t   = blockIdx.x * 256 + threadIdx.x;
    const int c   = t & 31;
    const int hw  = t >> 5;
    const int lhw = threadIdx.x >> 5;
    const int nhw = (ABG * 256) >> 5;
    const int per = (E + nhw - 1) / nhw;
    {
        float* pS = &sS[0][0];
        for (int i = threadIdx.x; i < 8 * SPP; i += 256) pS[i] = 0.f;
    }
    __syncthreads();
    float* base = &sS[lhw][0];
    for (int r = 0; r < REP; ++r) {
        int e0 = hw * per + ((r * 37) & 63);
        int e1 = e0 + per; if (e1 > E) e1 = E;
        for (int e = e0; e + 4 <= e1; e += 4) {
            int i0 = nidx[e],     i1 = nidx[e + 1];
            int i2 = nidx[e + 2], i3 = nidx[e + 3];
            int q0 = nkidx[e],     q1 = nkidx[e + 1];
            int q2 = nkidx[e + 2], q3 = nkidx[e + 3];
            float m0 = importance[i0], m1 = importance[i1];
            float m2 = importance[i2], m3 = importance[i3];
            float f0 = feats[(size_t)i0 * CIN + c];
            float f1 = feats[(size_t)i1 * CIN + c];
            float f2 = feats[(size_t)i2 * CIN + c];
            float f3 = feats[(size_t)i3 * CIN + c];
            atomicAdd(base + q0 * CIN + c, f0);
            atomicAdd(base + KC * CIN + q0 * CIN + c, f0 * m0);
            atomicAdd(base + q1 * CIN + c, f1);
            atomicAdd(base + KC * CIN + q1 * CIN + c, f1 * m1);
            atomicAdd(base + q2 * CIN + c, f2);
            atomicAdd(base + KC * CIN + q2 * CIN + c, f2 * m2);
            atomicAdd(base + q3 * CIN + c, f3);
            atomicAdd(base + KC * CIN + q3 * CIN + c, f3 * m3);
        }
    }
    __syncthreads();
    dump[t] = sS[lhw][c];
}

// ===========================================================================
// REAL PIPELINE — round 5's proven 596 µs path (edge-parallel + epilogue).
// ===========================================================================
__global__ void pack_weights(const float* __restrict__ Wa,
                             const float* __restrict__ Wb,
                             float* __restrict__ Wt) {
    int t = blockIdx.x * blockDim.x + threadIdx.x;
    if (t >= COUT * KC * CIN) return;
    int f = t / (KC * CIN);
    int r = t % (KC * CIN);
    float v = (f < CA) ? Wa[r * CA + f] : Wb[r * CB + (f - CA)];
    Wt[f * WSTR + r] = v;
}

__global__ __launch_bounds__(256) void edge_accum(
    const float* __restrict__ feats, const float* __restrict__ importance,
    const int* __restrict__ nidx, const int* __restrict__ nkidx,
    const int* __restrict__ noidx,
    float* __restrict__ Sa, float* __restrict__ Sb,
    float* __restrict__ impAcc, int E)
{
    const int t   = blockIdx.x * 256 + threadIdx.x;
    const int c   = t & 31;
    const int hw  = t >> 5;
    const int nhw = (gridDim.x * 256) >> 5;
    int per = (E + nhw - 1) / nhw;
    int e0  = hw * per;
    int e1  = e0 + per; if (e1 > E) e1 = E;
    if (e0 >= E) return;

    int e = e0;
    for (; e + 3 < e1; e += 4) {
        int n0 = noidx[e],     n1 = noidx[e + 1];
        int n2 = noidx[e + 2], n3 = noidx[e + 3];
        int i0 = nidx[e],      i1 = nidx[e + 1];
        int i2 = nidx[e + 2],  i3 = nidx[e + 3];
        int q0 = nkidx[e],     q1 = nkidx[e + 1];
        int q2 = nkidx[e + 2], q3 = nkidx[e + 3];
        float m0 = importance[i0], m1 = importance[i1];
        float m2 = importance[i2], m3 = importance[i3];
        float f0 = feats[(size_t)i0 * CIN + c];
        float f1 = feats[(size_t)i1 * CIN + c];
        float f2 = feats[(size_t)i2 * CIN + c];
        float f3 = feats[(size_t)i3 * CIN + c];
        size_t b0 = ((size_t)n0 * KC + q0) * CIN + c;
        size_t b1 = ((size_t)n1 * KC + q1) * CIN + c;
        size_t b2 = ((size_t)n2 * KC + q2) * CIN + c;
        size_t b3 = ((size_t)n3 * KC + q3) * CIN + c;
        atomicAdd(&Sa[b0], f0);  atomicAdd(&Sb[b0], f0 * m0);
        atomicAdd(&Sa[b1], f1);  atomicAdd(&Sb[b1], f1 * m1);
        atomicAdd(&Sa[b2], f2);  atomicAdd(&Sb[b2], f2 * m2);
        atomicAdd(&Sa[b3], f3);  atomicAdd(&Sb[b3], f3 * m3);
        if (c == 0) {
            atomicAdd(&impAcc[n0], m0);
            atomicAdd(&impAcc[n1], m1);
            atomicAdd(&impAcc[n2], m2);
            atomicAdd(&impAcc[n3], m3);
        }
    }
    for (; e < e1; ++e) {
        int   n0 = noidx[e], i0 = nidx[e], q0 = nkidx[e];
        float m0 = importance[i0];
        float f0 = feats[(size_t)i0 * CIN + c];
        size_t b0 = ((size_t)n0 * KC + q0) * CIN + c;
        atomicAdd(&Sa[b0], f0);
        atomicAdd(&Sb[b0], f0 * m0);
        if (c == 0) atomicAdd(&impAcc[n0], m0);
    }
}

__global__ __launch_bounds__(256) void epilogue(
    const float* __restrict__ Sa, const float* __restrict__ Sb,
    const float* __restrict__ impAcc, const float* __restrict__ Wt,
    const float* __restrict__ ba, const float* __restrict__ bb,
    float* __restrict__ outf, float* __restrict__ outimp, int nout)
{
    __shared__ __align__(16) float sW[COUT * WSTR];   // 37376 B
    {
        const float4* src = reinterpret_cast<const float4*>(Wt);
        float4*       dst = reinterpret_cast<float4*>(sW);
        for (int i = threadIdx.x; i < COUT * WSTR / 4; i += 256) dst[i] = src[i];
    }
    __syncthreads();

    const int wave = threadIdx.x >> 6;
    const int lane = threadIdx.x & 63;
    const int f    = lane & 31;
    const int h    = lane >> 5;
    const int n    = blockIdx.x * 4 + wave;
    if (n >= nout) return;

    float impTot = impAcc[n];
    float denom  = impTot > 0.f ? impTot : 1.f;

    const float* Sbase = ((f < CA) ? Sa : Sb) + (size_t)n * (KC * CIN);
    const float* Wbase = sW + f * WSTR;
    float acc0 = 0.f, acc1 = 0.f, acc2 = 0.f, acc3 = 0.f;
#pragma unroll
    for (int k = 0; k < KC; ++k) {
        int off = k * CIN + h * 16;
        float4 s0 = *reinterpret_cast<const float4*>(Sbase + off);
        float4 s1 = *reinterpret_cast<const float4*>(Sbase + off + 4);
        float4 s2 = *reinterpret_cast<const float4*>(Sbase + off + 8);
        float4 s3 = *reinterpret_cast<const float4*>(Sbase + off + 12);
        float4 w0 = *reinterpret_cast<const float4*>(Wbase + off);
        float4 w1 = *reinterpret_cast<const float4*>(Wbase + off + 4);
        float4 w2 = *reinterpret_cast<const float4*>(Wbase + off + 8);
        float4 w3 = *reinterpret_cast<const float4*>(Wbase + off + 12);
        acc0 = fmaf(s0.x, w0.x, fmaf(s0.y, w0.y, fmaf(s0.z, w0.z, fmaf(s0.w, w0.w, acc0))));
        acc1 = fmaf(s1.x, w1.x, fmaf(s1.y, w1.y, fmaf(s1.z, w1.z, fmaf(s1.w, w1.w, acc1))));
        acc2 = fmaf(s2.x, w2.x, fmaf(s2.y, w2.y, fmaf(s2.z, w2.z, fmaf(s2.w, w2.w, acc2))));
        acc3 = fmaf(s3.x, w3.x, fmaf(s3.y, w3.y, fmaf(s3.z, w3.z, fmaf(s3.w, w3.w, acc3))));
    }
    float acc = (acc0 + acc1) + (acc2 + acc3);
    float tot = acc + __shfl_xor(acc, 32, 64);

    if (h == 0) {
        float res = (f < CA) ? (tot + ba[f]) : (tot / denom + bb[f - CA]);
        outf[(size_t)n * COUT + f] = fmaxf(res, 0.f);
    }
    if (lane == 0) outimp[n] = impTot;
}

// ===========================================================================
// Fallback (round-6 fused) if ws can't hold scratch — known-correct.
// ===========================================================================
static constexpr int PPB = 16;
static constexpr int TPB = 512;
static constexpr int NHW = TPB / 32;

__global__ void build_rowptr(const int* __restrict__ oidx, int* __restrict__ rp,
                             int E, int nout) {
    int e = blockIdx.x * blockDim.x + threadIdx.x;
    if (e >= E) return;
    int cur  = oidx[e];
    int prev = (e == 0) ? -1 : oidx[e - 1];
    for (int id = prev + 1; id <= cur; ++id) rp[id] = e;
    if (e == E - 1) {
        for (int id = cur + 1; id <= nout; ++id) rp[id] = E;
    }
}

__global__ __launch_bounds__(TPB) void fused_block(
    const float* __restrict__ feats, const float* __restrict__ importance,
    const float* __restrict__ Wt, const float* __restrict__ ba,
    const float* __restrict__ bb,
    const int* __restrict__ nidx, const int* __restrict__ nkidx,
    const int* __restrict__ noidx, const int* __restrict__ rp,
    float* __restrict__ outf, float* __restrict__ outimp, int nout)
{
    __shared__ __align__(16) float sW[COUT * WSTR];
    __shared__ __align__(16) float sS[PPB][2][KC * CIN];
    __shared__ float sImp[PPB];

    const int tid = threadIdx.x;
    const int hw  = tid >> 5;
    const int c   = tid & 31;
    const int p0  = blockIdx.x * PPB;

    {
        const float4* src = reinterpret_cast<const float4*>(Wt);
        float4*       dst = reinterpret_cast<float4*>(sW);
        for (int i = tid; i < COUT * WSTR / 4; i += TPB) dst[i] = src[i];
        float* pS = &sS[0][0][0];
        for (int i = tid; i < PPB * 2 * KC * CIN; i += TPB) pS[i] = 0.f;
        if (tid < PPB) sImp[tid] = 0.f;
    }
    __syncthreads();

    const int pend   = (p0 + PPB < nout) ? (p0 + PPB) : nout;
    const int estart = rp[p0];
    const int eend   = rp[pend];
    const int cnt    = eend - estart;
    const int per    = (cnt + NHW - 1) / NHW;
    int a = estart + hw * per;
    int b = a + per; if (b > eend) b = eend;

    float* S0 = &sS[0][0][0];
    for (int e = a; e < b; ++e) {
        int   n0 = noidx[e], i0 = nidx[e], q0 = nkidx[e];
        float m0 = importance[i0];
        float f0 = feats[(size_t)i0 * CIN + c];
        float* bp = S0 + (n0 - p0) * (2 * KC * CIN) + q0 * CIN + c;
        atomicAdd(bp, f0);
        atomicAdd(bp + KC * CIN, f0 * m0);
        if (c == 0) atomicAdd(&sImp[n0 - p0], m0);
    }
    __syncthreads();

    const int wave = tid >> 6;
    const int lane = tid & 63;
    const int f    = lane & 31;
    const int h    = lane >> 5;
#pragma unroll
    for (int rep = 0; rep < 2; ++rep) {
        const int slot = wave * 2 + rep;
        const int n    = p0 + slot;
        if (n >= nout) break;
        float impTot = sImp[slot];
        float denom  = impTot > 0.f ? impTot : 1.f;
        const float* Sbase = &sS[slot][(f < CA) ? 0 : 1][0];
        const float* Wbase = sW + f * WSTR;
        float acc = 0.f;
#pragma unroll
        for (int k = 0; k < KC; ++k) {
            int off = k * CIN + h * 16;
#pragma unroll
            for (int j = 0; j < 16; ++j) acc = fmaf(Sbase[off + j], Wbase[off + j], acc);
        }
        float tot = acc + __shfl_xor(acc, 32, 64);
        if (h == 0) {
            float res = (f < CA) ? (tot + ba[f]) : (tot / denom + bb[f - CA]);
            outf[(size_t)n * COUT + f] = fmaxf(res, 0.f);
        }
        if (lane == 0) outimp[n] = impTot;
    }
}

// ---------------------------------------------------------------------------
extern "C" void kernel_launch(void* const* d_in, const int* in_sizes, int n_in,
                              void* d_out, int out_size, void* d_ws, size_t ws_size,
                              hipStream_t stream) {
    const float* feats      = (const float*)d_in[0];
    const float* importance = (const float*)d_in[1];
    const float* Wa         = (const float*)d_in[2];
    const float* ba         = (const float*)d_in[3];
    const float* Wb         = (const float*)d_in[4];
    const float* bb         = (const float*)d_in[5];
    const int*   nidx       = (const int*)d_in[6];
    const int*   nkidx      = (const int*)d_in[7];
    const int*   noidx      = (const int*)d_in[8];

    const int E    = in_sizes[6];
    const int nout = out_size / (COUT + 1);

    float* outf   = (float*)d_out;
    float* outimp = outf + (size_t)nout * COUT;

    // ws layout (round-5): Sa | Sb | impAcc | Wt
    const size_t sa_b    = (size_t)nout * KC * CIN * sizeof(float);
    const size_t off_sb  = (sa_b + 255) & ~(size_t)255;
    const size_t off_imp = (off_sb + sa_b + 255) & ~(size_t)255;
    const size_t off_wt  = (off_imp + (size_t)nout * sizeof(float) + 255) & ~(size_t)255;
    const size_t need    = off_wt + (size_t)COUT * WSTR * sizeof(float);

    if (ws_size >= need) {
        float* Sa     = (float*)d_ws;
        float* Sb     = (float*)((char*)d_ws + off_sb);
        float* impAcc = (float*)((char*)d_ws + off_imp);
        float* Wt     = (float*)((char*)d_ws + off_wt);
        float* dump   = (float*)d_ws;    // ablation dump; overwritten by memset

        // --- diagnostic ablations (results discarded) ---
        ab_stream<<<ABG, 256, 0, stream>>>(feats, importance, nidx, nkidx, dump, E);
        ab_streamldsS<<<ABG, 256, 0, stream>>>(feats, importance, nidx, nkidx, dump, E);

        // --- real pipeline (round 5) ---
        hipMemsetAsync(d_ws, 0, off_wt, stream);
        pack_weights<<<(COUT * KC * CIN + 255) / 256, 256, 0, stream>>>(Wa, Wb, Wt);
        edge_accum<<<ABG, 256, 0, stream>>>(feats, importance, nidx, nkidx,
                                            noidx, Sa, Sb, impAcc, E);
        epilogue<<<(nout + 3) / 4, 256, 0, stream>>>(Sa, Sb, impAcc, Wt, ba, bb,
                                                     outf, outimp, nout);
    } else {
        int*   rp = (int*)d_ws;
        size_t rp_bytes = ((size_t)(nout + 1) * sizeof(int) + 255) & ~(size_t)255;
        float* Wt = (float*)((char*)d_ws + rp_bytes);

        build_rowptr<<<(E + 255) / 256, 256, 0, stream>>>(noidx, rp, E, nout);
        pack_weights<<<(COUT * KC * CIN + 255) / 256, 256, 0, stream>>>(Wa, Wb, Wt);
        fused_block<<<(nout + PPB - 1) / PPB, TPB, 0, stream>>>(
            feats, importance, Wt, ba, bb, nidx, nkidx, noidx, rp,
            outf, outimp, nout);
    }
}

// Round 10
// 279.278 us; speedup vs baseline: 32.1711x; 32.1711x over previous
//
#include <hip/hip_runtime.h>

static constexpr int KC   = 9;    // kernel bins
static constexpr int CIN  = 32;   // input channels
static constexpr int CA   = 24;   // branch-a out channels
static constexpr int CB   = 8;    // branch-b out channels
static constexpr int COUT = 32;   // CA + CB
static constexpr int WSTR = KC * CIN + 4;   // 292 dwords: packed-W row stride
static constexpr int SPP  = 2 * KC * CIN;   // 576 dwords S per point (Sa|Sb)

// ---------------------------------------------------------------------------
// Kernel 1: CSR row pointer from sorted neighbors_out_index.
// ---------------------------------------------------------------------------
__global__ void build_rowptr(const int* __restrict__ oidx, int* __restrict__ rp,
                             int E, int nout) {
    int e = blockIdx.x * blockDim.x + threadIdx.x;
    if (e >= E) return;
    int cur  = oidx[e];
    int prev = (e == 0) ? -1 : oidx[e - 1];
    for (int id = prev + 1; id <= cur; ++id) rp[id] = e;
    if (e == E - 1) {
        for (int id = cur + 1; id <= nout; ++id) rp[id] = E;
    }
}

// ---------------------------------------------------------------------------
// Kernel 2: pack W_a [9][32][24], W_b [9][32][8] into Wt[f][k][c], row
// stride WSTR dwords (f-major), for the per-feature epilogue.
// ---------------------------------------------------------------------------
__global__ void pack_weights(const float* __restrict__ Wa,
                             const float* __restrict__ Wb,
                             float* __restrict__ Wt) {
    int t = blockIdx.x * blockDim.x + threadIdx.x;
    if (t >= COUT * KC * CIN) return;
    int f = t / (KC * CIN);
    int r = t % (KC * CIN);            // k*32 + c
    float v = (f < CA) ? Wa[r * CA + f] : Wb[r * CB + (f - CA)];
    Wt[f * WSTR + r] = v;
}

// ---------------------------------------------------------------------------
// Kernel A: register-predicated S accumulation. NO atomics anywhere.
// One wave per point (grid-stride). Lane layout: c = lane&31 (channel),
// h = lane>>5 (edge parity). Each lane accumulates sa[9]/sb[9] in REGISTERS
// via 9-way predicated FMA (q is per-lane; no branches, no memory RMW).
// Flush: shfl_xor(32) half-combine + plain coalesced stores. Every S slot
// and impAcc slot is written -> no memset required.
// ---------------------------------------------------------------------------
__global__ __launch_bounds__(256) void accum_reg(
    const float* __restrict__ feats, const float* __restrict__ importance,
    const int* __restrict__ nidx, const int* __restrict__ nkidx,
    const int* __restrict__ rp,
    float* __restrict__ S, float* __restrict__ impAcc, int nout)
{
    const int gw   = (blockIdx.x * 256 + threadIdx.x) >> 6;  // global wave id
    const int NW   = (gridDim.x * 256) >> 6;
    const int lane = threadIdx.x & 63;
    const int c    = lane & 31;
    const int h    = lane >> 5;

    for (int n = gw; n < nout; n += NW) {
        const int start = rp[n];
        const int end   = rp[n + 1];

        float sa[KC], sb[KC];
#pragma unroll
        for (int k = 0; k < KC; ++k) { sa[k] = 0.f; sb[k] = 0.f; }
        float accImp = 0.f;

        // 2 edges per wave-iteration (one per half); wave-uniform bounds.
        for (int eb = start; eb < end; eb += 2) {
            int  e     = eb + h;
            bool valid = (e < end);
            int  ec    = valid ? e : (end - 1);   // end>start when loop runs
            int   idx = nidx[ec];
            int   q   = nkidx[ec];
            float m   = importance[idx];
            float f   = feats[(size_t)idx * CIN + c];
            if (!valid) { m = 0.f; f = 0.f; }
            accImp += m;
            float fm = f * m;
#pragma unroll
            for (int k = 0; k < KC; ++k) {
                float mk = (q == k) ? 1.0f : 0.0f;
                sa[k] = fmaf(mk, f,  sa[k]);
                sb[k] = fmaf(mk, fm, sb[k]);
            }
        }

        // combine the two halves and store (plain coalesced stores)
        float impTot = accImp + __shfl_xor(accImp, 32, 64);
        float* Sp = S + (size_t)n * SPP;
#pragma unroll
        for (int k = 0; k < KC; ++k) {
            float ta = sa[k] + __shfl_xor(sa[k], 32, 64);
            float tb = sb[k] + __shfl_xor(sb[k], 32, 64);
            if (h == 0) {
                Sp[k * CIN + c]            = ta;
                Sp[KC * CIN + k * CIN + c] = tb;
            }
        }
        if (lane == 0) impAcc[n] = impTot;
    }
}

// ---------------------------------------------------------------------------
// Kernel B: per-feature epilogue (proven, round 7). 512 threads / 8 waves
// (one point each), W in LDS (37.4 KB). S layout [n][2][288].
// ---------------------------------------------------------------------------
__global__ __launch_bounds__(512) void epilogue(
    const float* __restrict__ S, const float* __restrict__ impAcc,
    const float* __restrict__ Wt, const float* __restrict__ ba,
    const float* __restrict__ bb,
    float* __restrict__ outf, float* __restrict__ outimp, int nout)
{
    __shared__ __align__(16) float sW[COUT * WSTR];   // 37376 B
    {
        const float4* src = reinterpret_cast<const float4*>(Wt);
        float4*       dst = reinterpret_cast<float4*>(sW);
        for (int i = threadIdx.x; i < COUT * WSTR / 4; i += 512) dst[i] = src[i];
    }
    __syncthreads();

    const int wave = threadIdx.x >> 6;
    const int lane = threadIdx.x & 63;
    const int f    = lane & 31;
    const int h    = lane >> 5;
    const int n    = blockIdx.x * 8 + wave;
    if (n >= nout) return;

    float impTot = impAcc[n];
    float denom  = impTot > 0.f ? impTot : 1.f;

    const float* Sbase = S + (size_t)n * SPP + ((f < CA) ? 0 : KC * CIN);
    const float* Wbase = sW + f * WSTR;
    float acc0 = 0.f, acc1 = 0.f, acc2 = 0.f, acc3 = 0.f;
#pragma unroll
    for (int k = 0; k < KC; ++k) {
        int off = k * CIN + h * 16;
        float4 s0 = *reinterpret_cast<const float4*>(Sbase + off);
        float4 s1 = *reinterpret_cast<const float4*>(Sbase + off + 4);
        float4 s2 = *reinterpret_cast<const float4*>(Sbase + off + 8);
        float4 s3 = *reinterpret_cast<const float4*>(Sbase + off + 12);
        float4 w0 = *reinterpret_cast<const float4*>(Wbase + off);
        float4 w1 = *reinterpret_cast<const float4*>(Wbase + off + 4);
        float4 w2 = *reinterpret_cast<const float4*>(Wbase + off + 8);
        float4 w3 = *reinterpret_cast<const float4*>(Wbase + off + 12);
        acc0 = fmaf(s0.x, w0.x, fmaf(s0.y, w0.y, fmaf(s0.z, w0.z, fmaf(s0.w, w0.w, acc0))));
        acc1 = fmaf(s1.x, w1.x, fmaf(s1.y, w1.y, fmaf(s1.z, w1.z, fmaf(s1.w, w1.w, acc1))));
        acc2 = fmaf(s2.x, w2.x, fmaf(s2.y, w2.y, fmaf(s2.z, w2.z, fmaf(s2.w, w2.w, acc2))));
        acc3 = fmaf(s3.x, w3.x, fmaf(s3.y, w3.y, fmaf(s3.z, w3.z, fmaf(s3.w, w3.w, acc3))));
    }
    float acc = (acc0 + acc1) + (acc2 + acc3);
    float tot = acc + __shfl_xor(acc, 32, 64);   // combine channel halves

    if (h == 0) {
        float res = (f < CA) ? (tot + ba[f]) : (tot / denom + bb[f - CA]);
        outf[(size_t)n * COUT + f] = fmaxf(res, 0.f);
    }
    if (lane == 0) outimp[n] = impTot;
}

// ===========================================================================
// Fallback (round-6 fused kernel) if ws can't hold the S scratch.
// ===========================================================================
static constexpr int PPB = 16;
static constexpr int TPB = 512;
static constexpr int NHW = TPB / 32;

__global__ __launch_bounds__(TPB) void fused_block(
    const float* __restrict__ feats, const float* __restrict__ importance,
    const float* __restrict__ Wt, const float* __restrict__ ba,
    const float* __restrict__ bb,
    const int* __restrict__ nidx, const int* __restrict__ nkidx,
    const int* __restrict__ noidx, const int* __restrict__ rp,
    float* __restrict__ outf, float* __restrict__ outimp, int nout)
{
    __shared__ __align__(16) float sW[COUT * WSTR];
    __shared__ __align__(16) float sS[PPB][2][KC * CIN];
    __shared__ float sImp[PPB];

    const int tid = threadIdx.x;
    const int hw  = tid >> 5;
    const int c   = tid & 31;
    const int p0  = blockIdx.x * PPB;

    {
        const float4* src = reinterpret_cast<const float4*>(Wt);
        float4*       dst = reinterpret_cast<float4*>(sW);
        for (int i = tid; i < COUT * WSTR / 4; i += TPB) dst[i] = src[i];
        float* pS = &sS[0][0][0];
        for (int i = tid; i < PPB * 2 * KC * CIN; i += TPB) pS[i] = 0.f;
        if (tid < PPB) sImp[tid] = 0.f;
    }
    __syncthreads();

    const int pend   = (p0 + PPB < nout) ? (p0 + PPB) : nout;
    const int estart = rp[p0];
    const int eend   = rp[pend];
    const int cnt    = eend - estart;
    const int per    = (cnt + NHW - 1) / NHW;
    int a = estart + hw * per;
    int b = a + per; if (b > eend) b = eend;

    float* S0 = &sS[0][0][0];
    for (int e = a; e < b; ++e) {
        int   n0 = noidx[e], i0 = nidx[e], q0 = nkidx[e];
        float m0 = importance[i0];
        float f0 = feats[(size_t)i0 * CIN + c];
        float* bp = S0 + (n0 - p0) * (2 * KC * CIN) + q0 * CIN + c;
        atomicAdd(bp, f0);
        atomicAdd(bp + KC * CIN, f0 * m0);
        if (c == 0) atomicAdd(&sImp[n0 - p0], m0);
    }
    __syncthreads();

    const int wave = tid >> 6;
    const int lane = tid & 63;
    const int f    = lane & 31;
    const int h    = lane >> 5;
#pragma unroll
    for (int rep = 0; rep < 2; ++rep) {
        const int slot = wave * 2 + rep;
        const int n    = p0 + slot;
        if (n >= nout) break;
        float impTot = sImp[slot];
        float denom  = impTot > 0.f ? impTot : 1.f;
        const float* Sbase = &sS[slot][(f < CA) ? 0 : 1][0];
        const float* Wbase = sW + f * WSTR;
        float acc = 0.f;
#pragma unroll
        for (int k = 0; k < KC; ++k) {
            int off = k * CIN + h * 16;
#pragma unroll
            for (int j = 0; j < 16; ++j) acc = fmaf(Sbase[off + j], Wbase[off + j], acc);
        }
        float tot = acc + __shfl_xor(acc, 32, 64);
        if (h == 0) {
            float res = (f < CA) ? (tot + ba[f]) : (tot / denom + bb[f - CA]);
            outf[(size_t)n * COUT + f] = fmaxf(res, 0.f);
        }
        if (lane == 0) outimp[n] = impTot;
    }
}

// ---------------------------------------------------------------------------
extern "C" void kernel_launch(void* const* d_in, const int* in_sizes, int n_in,
                              void* d_out, int out_size, void* d_ws, size_t ws_size,
                              hipStream_t stream) {
    const float* feats      = (const float*)d_in[0];
    const float* importance = (const float*)d_in[1];
    const float* Wa         = (const float*)d_in[2];
    const float* ba         = (const float*)d_in[3];
    const float* Wb         = (const float*)d_in[4];
    const float* bb         = (const float*)d_in[5];
    const int*   nidx       = (const int*)d_in[6];
    const int*   nkidx      = (const int*)d_in[7];
    const int*   noidx      = (const int*)d_in[8];

    const int E    = in_sizes[6];
    const int nout = out_size / (COUT + 1);

    float* outf   = (float*)d_out;
    float* outimp = outf + (size_t)nout * COUT;

    // ws layout: S [nout*576 f] | impAcc [nout f] | Wt | rp [(nout+1) i]
    const size_t off_imp = ((size_t)nout * SPP * sizeof(float) + 255) & ~(size_t)255;
    const size_t off_wt  = (off_imp + (size_t)nout * sizeof(float) + 255) & ~(size_t)255;
    const size_t off_rp  = (off_wt + (size_t)COUT * WSTR * sizeof(float) + 255) & ~(size_t)255;
    const size_t need    = off_rp + (size_t)(nout + 1) * sizeof(int);

    if (ws_size >= need) {
        float* S      = (float*)d_ws;
        float* impAcc = (float*)((char*)d_ws + off_imp);
        float* Wt     = (float*)((char*)d_ws + off_wt);
        int*   rp     = (int*)((char*)d_ws + off_rp);

        build_rowptr<<<(E + 255) / 256, 256, 0, stream>>>(noidx, rp, E, nout);
        pack_weights<<<(COUT * KC * CIN + 255) / 256, 256, 0, stream>>>(Wa, Wb, Wt);
        accum_reg<<<2048, 256, 0, stream>>>(
            feats, importance, nidx, nkidx, rp, S, impAcc, nout);
        epilogue<<<(nout + 7) / 8, 512, 0, stream>>>(
            S, impAcc, Wt, ba, bb, outf, outimp, nout);
    } else {
        int*   rp = (int*)d_ws;
        size_t rp_bytes = ((size_t)(nout + 1) * sizeof(int) + 255) & ~(size_t)255;
        float* Wt = (float*)((char*)d_ws + rp_bytes);

        build_rowptr<<<(E + 255) / 256, 256, 0, stream>>>(noidx, rp, E, nout);
        pack_weights<<<(COUT * KC * CIN + 255) / 256, 256, 0, stream>>>(Wa, Wb, Wt);
        fused_block<<<(nout + PPB - 1) / PPB, TPB, 0, stream>>>(
            feats, importance, Wt, ba, bb, nidx, nkidx, noidx, rp,
            outf, outimp, nout);
    }
}

// Round 11
// 251.100 us; speedup vs baseline: 35.7812x; 1.1122x over previous
//
#include <hip/hip_runtime.h>

static constexpr int KC   = 9;    // kernel bins
static constexpr int CIN  = 32;   // input channels
static constexpr int CA   = 24;   // branch-a out channels
static constexpr int CB   = 8;    // branch-b out channels
static constexpr int COUT = 32;   // CA + CB
static constexpr int SPP  = 2 * KC * CIN;   // 576 dwords S per point (Sa|Sb)
static constexpr int KCC  = KC * CIN;       // 288

// ---------------------------------------------------------------------------
// Kernel 1: CSR row pointer from sorted neighbors_out_index.
// ---------------------------------------------------------------------------
__global__ void build_rowptr(const int* __restrict__ oidx, int* __restrict__ rp,
                             int E, int nout) {
    int e = blockIdx.x * blockDim.x + threadIdx.x;
    if (e >= E) return;
    int cur  = oidx[e];
    int prev = (e == 0) ? -1 : oidx[e - 1];
    for (int id = prev + 1; id <= cur; ++id) rp[id] = e;
    if (e == E - 1) {
        for (int id = cur + 1; id <= nout; ++id) rp[id] = E;
    }
}

// ---------------------------------------------------------------------------
// Kernel 2: pack W_a [9][32][24], W_b [9][32][8] into Wc[kc][f] flat
// (f-contiguous, 32 wide). Epilogue reads it via wave-uniform s_load only,
// so no bank/stride considerations.
// ---------------------------------------------------------------------------
__global__ void pack_weights(const float* __restrict__ Wa,
                             const float* __restrict__ Wb,
                             float* __restrict__ Wc) {
    int t = blockIdx.x * blockDim.x + threadIdx.x;
    if (t >= KCC * COUT) return;
    int f  = t & (COUT - 1);
    int kc = t >> 5;
    Wc[t] = (f < CA) ? Wa[kc * CA + f] : Wb[kc * CB + (f - CA)];
}

// ---------------------------------------------------------------------------
// Kernel 3: per-edge importance pre-gather (removes one dependent gather
// level from the hot accumulation loop). Coalesced read/write.
// ---------------------------------------------------------------------------
__global__ void gather_imp(const int* __restrict__ nidx,
                           const float* __restrict__ importance,
                           float* __restrict__ imp_e, int E) {
    int e = blockIdx.x * blockDim.x + threadIdx.x;
    if (e < E) imp_e[e] = importance[nidx[e]];
}

// ---------------------------------------------------------------------------
// Kernel A: register-predicated S accumulation (NO atomics — round-9 win).
// One wave per point (grid-stride). c = lane&31 (channel), h = lane>>5
// (edge parity). sa[9]/sb[9] in registers via 9-way predicated FMA.
// Flush: shfl_xor(32) + plain coalesced stores; every slot written.
// ---------------------------------------------------------------------------
__global__ __launch_bounds__(256) void accum_reg(
    const float* __restrict__ feats, const float* __restrict__ imp_e,
    const int* __restrict__ nidx, const int* __restrict__ nkidx,
    const int* __restrict__ rp,
    float* __restrict__ S, float* __restrict__ impAcc, int nout)
{
    const int gw   = (blockIdx.x * 256 + threadIdx.x) >> 6;  // global wave id
    const int NW   = (gridDim.x * 256) >> 6;
    const int lane = threadIdx.x & 63;
    const int c    = lane & 31;
    const int h    = lane >> 5;

    for (int n = gw; n < nout; n += NW) {
        const int start = rp[n];
        const int end   = rp[n + 1];

        float sa[KC], sb[KC];
#pragma unroll
        for (int k = 0; k < KC; ++k) { sa[k] = 0.f; sb[k] = 0.f; }
        float accImp = 0.f;

        for (int eb = start; eb < end; eb += 2) {
            int  e     = eb + h;
            bool valid = (e < end);
            int  ec    = valid ? e : (end - 1);   // end>start when loop runs
            int   idx = nidx[ec];
            int   q   = nkidx[ec];
            float m   = imp_e[ec];                // coalesced (pre-gathered)
            float f   = feats[(size_t)idx * CIN + c];
            if (!valid) { m = 0.f; f = 0.f; }
            accImp += m;
            float fm = f * m;
#pragma unroll
            for (int k = 0; k < KC; ++k) {
                float mk = (q == k) ? 1.0f : 0.0f;
                sa[k] = fmaf(mk, f,  sa[k]);
                sb[k] = fmaf(mk, fm, sb[k]);
            }
        }

        float impTot = accImp + __shfl_xor(accImp, 32, 64);
        float* Sp = S + (size_t)n * SPP;
#pragma unroll
        for (int k = 0; k < KC; ++k) {
            float ta = sa[k] + __shfl_xor(sa[k], 32, 64);
            float tb = sb[k] + __shfl_xor(sb[k], 32, 64);
            if (h == 0) {
                Sp[k * CIN + c]       = ta;
                Sp[KCC + k * CIN + c] = tb;
            }
        }
        if (lane == 0) impAcc[n] = impTot;
    }
}

// ---------------------------------------------------------------------------
// Kernel B: lane-per-point GEMM-style epilogue. Each lane owns one output
// point and its full acc[32]; S is a per-lane sequential row stream (lines
// fully consumed); W addresses are WAVE-UNIFORM -> s_load through K$,
// amortized across all 64 points of the wave. No LDS at all.
// ---------------------------------------------------------------------------
__global__ __launch_bounds__(256) void epilogue_g(
    const float* __restrict__ S, const float* __restrict__ impAcc,
    const float* __restrict__ Wc, const float* __restrict__ ba,
    const float* __restrict__ bb,
    float* __restrict__ outf, float* __restrict__ outimp, int nout)
{
    const int gtid  = blockIdx.x * 256 + threadIdx.x;
    const bool valid = (gtid < nout);
    const int n     = valid ? gtid : (nout - 1);

    const float* Sp = S + (size_t)n * SPP;

    float acc[COUT];
#pragma unroll
    for (int j = 0; j < COUT; ++j) acc[j] = 0.f;

    for (int t = 0; t < KCC; t += 4) {
        float4 va = *reinterpret_cast<const float4*>(Sp + t);
        float4 vb = *reinterpret_cast<const float4*>(Sp + KCC + t);
        float sav[4] = {va.x, va.y, va.z, va.w};
        float sbv[4] = {vb.x, vb.y, vb.z, vb.w};
#pragma unroll
        for (int u = 0; u < 4; ++u) {
            const float* w = Wc + (t + u) * COUT;   // wave-uniform -> s_load
#pragma unroll
            for (int j = 0; j < CA; ++j) acc[j] = fmaf(sav[u], w[j], acc[j]);
#pragma unroll
            for (int j = 0; j < CB; ++j)
                acc[CA + j] = fmaf(sbv[u], w[CA + j], acc[CA + j]);
        }
    }

    float impTot = impAcc[n];
    float denom  = impTot > 0.f ? impTot : 1.f;

    if (valid) {
        float res[COUT];
#pragma unroll
        for (int j = 0; j < CA; ++j) res[j] = fmaxf(acc[j] + ba[j], 0.f);
#pragma unroll
        for (int j = 0; j < CB; ++j)
            res[CA + j] = fmaxf(acc[CA + j] / denom + bb[j], 0.f);
        float4* op = reinterpret_cast<float4*>(outf + (size_t)n * COUT);
#pragma unroll
        for (int j4 = 0; j4 < 8; ++j4)
            op[j4] = make_float4(res[4 * j4], res[4 * j4 + 1],
                                 res[4 * j4 + 2], res[4 * j4 + 3]);
        outimp[n] = impTot;
    }
}

// ===========================================================================
// Fallback (round-6 fused kernel) if ws can't hold the S scratch.
// ===========================================================================
static constexpr int WSTR = KC * CIN + 4;
static constexpr int PPB = 16;
static constexpr int TPB = 512;
static constexpr int NHW = TPB / 32;

__global__ __launch_bounds__(TPB) void fused_block(
    const float* __restrict__ feats, const float* __restrict__ importance,
    const float* __restrict__ Wt, const float* __restrict__ ba,
    const float* __restrict__ bb,
    const int* __restrict__ nidx, const int* __restrict__ nkidx,
    const int* __restrict__ noidx, const int* __restrict__ rp,
    float* __restrict__ outf, float* __restrict__ outimp, int nout)
{
    __shared__ __align__(16) float sW[COUT * WSTR];
    __shared__ __align__(16) float sS[PPB][2][KC * CIN];
    __shared__ float sImp[PPB];

    const int tid = threadIdx.x;
    const int hw  = tid >> 5;
    const int c   = tid & 31;
    const int p0  = blockIdx.x * PPB;

    {
        float* pS = &sS[0][0][0];
        for (int i = tid; i < PPB * 2 * KC * CIN; i += TPB) pS[i] = 0.f;
        // pack weights straight from global (layout [f][k][c] w/ stride WSTR)
        for (int i = tid; i < COUT * KC * CIN; i += TPB) {
            int f = i / (KC * CIN);
            int r = i % (KC * CIN);
            sW[f * WSTR + r] = Wt[i];   // Wt here is flat [f][kc] pre-pack
        }
        if (tid < PPB) sImp[tid] = 0.f;
    }
    __syncthreads();

    const int pend   = (p0 + PPB < nout) ? (p0 + PPB) : nout;
    const int estart = rp[p0];
    const int eend   = rp[pend];
    const int cnt    = eend - estart;
    const int per    = (cnt + NHW - 1) / NHW;
    int a = estart + hw * per;
    int b = a + per; if (b > eend) b = eend;

    float* S0 = &sS[0][0][0];
    for (int e = a; e < b; ++e) {
        int   n0 = noidx[e], i0 = nidx[e], q0 = nkidx[e];
        float m0 = importance[i0];
        float f0 = feats[(size_t)i0 * CIN + c];
        float* bp = S0 + (n0 - p0) * (2 * KC * CIN) + q0 * CIN + c;
        atomicAdd(bp, f0);
        atomicAdd(bp + KC * CIN, f0 * m0);
        if (c == 0) atomicAdd(&sImp[n0 - p0], m0);
    }
    __syncthreads();

    const int wave = tid >> 6;
    const int lane = tid & 63;
    const int f    = lane & 31;
    const int h    = lane >> 5;
#pragma unroll
    for (int rep = 0; rep < 2; ++rep) {
        const int slot = wave * 2 + rep;
        const int n    = p0 + slot;
        if (n >= nout) break;
        float impTot = sImp[slot];
        float denom  = impTot > 0.f ? impTot : 1.f;
        const float* Sbase = &sS[slot][(f < CA) ? 0 : 1][0];
        const float* Wbase = sW + f * WSTR;
        float acc = 0.f;
#pragma unroll
        for (int k = 0; k < KC; ++k) {
            int off = k * CIN + h * 16;
#pragma unroll
            for (int j = 0; j < 16; ++j) acc = fmaf(Sbase[off + j], Wbase[off + j], acc);
        }
        float tot = acc + __shfl_xor(acc, 32, 64);
        if (h == 0) {
            float res = (f < CA) ? (tot + ba[f]) : (tot / denom + bb[f - CA]);
            outf[(size_t)n * COUT + f] = fmaxf(res, 0.f);
        }
        if (lane == 0) outimp[n] = impTot;
    }
}

// fallback needs W in [f][kc] flat order
__global__ void pack_weights_fkc(const float* __restrict__ Wa,
                                 const float* __restrict__ Wb,
                                 float* __restrict__ Wt) {
    int t = blockIdx.x * blockDim.x + threadIdx.x;
    if (t >= COUT * KC * CIN) return;
    int f = t / (KC * CIN);
    int r = t % (KC * CIN);
    Wt[t] = (f < CA) ? Wa[r * CA + f] : Wb[r * CB + (f - CA)];
}

// ---------------------------------------------------------------------------
extern "C" void kernel_launch(void* const* d_in, const int* in_sizes, int n_in,
                              void* d_out, int out_size, void* d_ws, size_t ws_size,
                              hipStream_t stream) {
    const float* feats      = (const float*)d_in[0];
    const float* importance = (const float*)d_in[1];
    const float* Wa         = (const float*)d_in[2];
    const float* ba         = (const float*)d_in[3];
    const float* Wb         = (const float*)d_in[4];
    const float* bb         = (const float*)d_in[5];
    const int*   nidx       = (const int*)d_in[6];
    const int*   nkidx      = (const int*)d_in[7];
    const int*   noidx      = (const int*)d_in[8];

    const int E    = in_sizes[6];
    const int nout = out_size / (COUT + 1);

    float* outf   = (float*)d_out;
    float* outimp = outf + (size_t)nout * COUT;

    // ws: S [nout*576 f] | impAcc [nout] | Wc [288*32] | rp [nout+1] | imp_e [E]
    const size_t off_imp = ((size_t)nout * SPP * sizeof(float) + 255) & ~(size_t)255;
    const size_t off_wc  = (off_imp + (size_t)nout * sizeof(float) + 255) & ~(size_t)255;
    const size_t off_rp  = (off_wc + (size_t)KCC * COUT * sizeof(float) + 255) & ~(size_t)255;
    const size_t off_ie  = (off_rp + (size_t)(nout + 1) * sizeof(int) + 255) & ~(size_t)255;
    const size_t need    = off_ie + (size_t)E * sizeof(float);

    if (ws_size >= need) {
        float* S      = (float*)d_ws;
        float* impAcc = (float*)((char*)d_ws + off_imp);
        float* Wc     = (float*)((char*)d_ws + off_wc);
        int*   rp     = (int*)((char*)d_ws + off_rp);
        float* imp_e  = (float*)((char*)d_ws + off_ie);

        build_rowptr<<<(E + 255) / 256, 256, 0, stream>>>(noidx, rp, E, nout);
        pack_weights<<<(KCC * COUT + 255) / 256, 256, 0, stream>>>(Wa, Wb, Wc);
        gather_imp<<<(E + 255) / 256, 256, 0, stream>>>(nidx, importance, imp_e, E);
        accum_reg<<<2048, 256, 0, stream>>>(
            feats, imp_e, nidx, nkidx, rp, S, impAcc, nout);
        epilogue_g<<<(nout + 255) / 256, 256, 0, stream>>>(
            S, impAcc, Wc, ba, bb, outf, outimp, nout);
    } else {
        int*   rp = (int*)d_ws;
        size_t rp_bytes = ((size_t)(nout + 1) * sizeof(int) + 255) & ~(size_t)255;
        float* Wt = (float*)((char*)d_ws + rp_bytes);

        build_rowptr<<<(E + 255) / 256, 256, 0, stream>>>(noidx, rp, E, nout);
        pack_weights_fkc<<<(COUT * KC * CIN + 255) / 256, 256, 0, stream>>>(Wa, Wb, Wt);
        fused_block<<<(nout + PPB - 1) / PPB, TPB, 0, stream>>>(
            feats, importance, Wt, ba, bb, nidx, nkidx, noidx, rp,
            outf, outimp, nout);
    }
}

// Round 12
// 155.392 us; speedup vs baseline: 57.8193x; 1.6159x over previous
//
#include <hip/hip_runtime.h>
#include <hip/hip_bf16.h>

static constexpr int KC   = 9;    // kernel bins
static constexpr int CIN  = 32;   // input channels
static constexpr int CA   = 24;   // branch-a out channels
static constexpr int CB   = 8;    // branch-b out channels
static constexpr int COUT = 32;   // CA + CB
static constexpr int KCC  = KC * CIN;       // 288
static constexpr int SPP  = 2 * KCC;        // 576 bf16 S entries per point

// ---------------------------------------------------------------------------
// Prep kernel: CSR row pointer + per-edge importance pre-gather + W pack,
// all edge/element-parallel in one launch.
// ---------------------------------------------------------------------------
__global__ void prep(const int* __restrict__ oidx, const int* __restrict__ nidx,
                     const float* __restrict__ importance,
                     const float* __restrict__ Wa, const float* __restrict__ Wb,
                     int* __restrict__ rp, float* __restrict__ imp_e,
                     float* __restrict__ Wc, int E, int nout) {
    int e = blockIdx.x * blockDim.x + threadIdx.x;
    if (e < E) {
        // rowptr scatter
        int cur  = oidx[e];
        int prev = (e == 0) ? -1 : oidx[e - 1];
        for (int id = prev + 1; id <= cur; ++id) rp[id] = e;
        if (e == E - 1) {
            for (int id = cur + 1; id <= nout; ++id) rp[id] = E;
        }
        // importance pre-gather
        imp_e[e] = importance[nidx[e]];
        // weight pack Wc[kc][f] (f-contiguous)
        if (e < KCC * COUT) {
            int f  = e & (COUT - 1);
            int kc = e >> 5;
            Wc[e] = (f < CA) ? Wa[kc * CA + f] : Wb[kc * CB + (f - CA)];
        }
    }
}

// ---------------------------------------------------------------------------
// Kernel A: scalar-q register accumulation. One wave per point (grid-stride);
// ONE edge per wave-iteration: all per-edge metadata is wave-uniform, so the
// bin select is a SCALAR branch chain guarding a compile-time-indexed v_add.
// Half 0 (lanes 0-31) accumulates Sa, half 1 accumulates Sb = f*m.
// Flush: bf16 convert + plain coalesced stores. No atomics, no shuffles.
// ---------------------------------------------------------------------------
__global__ __launch_bounds__(256) void accum_u(
    const float* __restrict__ feats, const float* __restrict__ imp_e,
    const int* __restrict__ nidx, const int* __restrict__ nkidx,
    const int* __restrict__ rp,
    __hip_bfloat16* __restrict__ S, float* __restrict__ impAcc, int nout)
{
    const int lane = threadIdx.x & 63;
    const int c    = lane & 31;
    const int h    = lane >> 5;
    int gw = (blockIdx.x * 256 + threadIdx.x) >> 6;
    gw = __builtin_amdgcn_readfirstlane(gw);          // uniform wave id
    const int NW = (gridDim.x * 256) >> 6;

    for (int n = gw; n < nout; n += NW) {
        const int start = rp[n];                      // uniform
        const int end   = rp[n + 1];                  // uniform

        float acc[KC];
#pragma unroll
        for (int k = 0; k < KC; ++k) acc[k] = 0.f;
        float accImp = 0.f;

#define EDGE_BODY(Q, V)                                                   \
        do {                                                              \
            if      ((Q) == 0) acc[0] += (V);                             \
            else if ((Q) == 1) acc[1] += (V);                             \
            else if ((Q) == 2) acc[2] += (V);                             \
            else if ((Q) == 3) acc[3] += (V);                             \
            else if ((Q) == 4) acc[4] += (V);                             \
            else if ((Q) == 5) acc[5] += (V);                             \
            else if ((Q) == 6) acc[6] += (V);                             \
            else               acc[7 + ((Q) & 1)] += (V);                 \
        } while (0)
        // note: q==7 -> acc[8]? careful: handle 7 and 8 explicitly below.

        int e = start;
        // 2-edge unroll: two independent feats loads in flight
        for (; e + 2 <= end; e += 2) {
            int q0 = __builtin_amdgcn_readfirstlane(nkidx[e]);
            int q1 = __builtin_amdgcn_readfirstlane(nkidx[e + 1]);
            int i0 = nidx[e], i1 = nidx[e + 1];
            float m0 = imp_e[e], m1 = imp_e[e + 1];
            float f0 = feats[(size_t)i0 * CIN + c];
            float f1 = feats[(size_t)i1 * CIN + c];
            float v0 = h ? f0 * m0 : f0;
            float v1 = h ? f1 * m1 : f1;
            accImp += m0 + m1;
            if      (q0 == 0) acc[0] += v0;
            else if (q0 == 1) acc[1] += v0;
            else if (q0 == 2) acc[2] += v0;
            else if (q0 == 3) acc[3] += v0;
            else if (q0 == 4) acc[4] += v0;
            else if (q0 == 5) acc[5] += v0;
            else if (q0 == 6) acc[6] += v0;
            else if (q0 == 7) acc[7] += v0;
            else              acc[8] += v0;
            if      (q1 == 0) acc[0] += v1;
            else if (q1 == 1) acc[1] += v1;
            else if (q1 == 2) acc[2] += v1;
            else if (q1 == 3) acc[3] += v1;
            else if (q1 == 4) acc[4] += v1;
            else if (q1 == 5) acc[5] += v1;
            else if (q1 == 6) acc[6] += v1;
            else if (q1 == 7) acc[7] += v1;
            else              acc[8] += v1;
        }
        if (e < end) {
            int q0 = __builtin_amdgcn_readfirstlane(nkidx[e]);
            int i0 = nidx[e];
            float m0 = imp_e[e];
            float f0 = feats[(size_t)i0 * CIN + c];
            float v0 = h ? f0 * m0 : f0;
            accImp += m0;
            if      (q0 == 0) acc[0] += v0;
            else if (q0 == 1) acc[1] += v0;
            else if (q0 == 2) acc[2] += v0;
            else if (q0 == 3) acc[3] += v0;
            else if (q0 == 4) acc[4] += v0;
            else if (q0 == 5) acc[5] += v0;
            else if (q0 == 6) acc[6] += v0;
            else if (q0 == 7) acc[7] += v0;
            else              acc[8] += v0;
        }
#undef EDGE_BODY

        // flush: half 0 -> Sa region, half 1 -> Sb region (bf16)
        __hip_bfloat16* Sp = S + (size_t)n * SPP + h * KCC + c;
#pragma unroll
        for (int k = 0; k < KC; ++k) Sp[k * CIN] = __float2bfloat16(acc[k]);
        if (lane == 0) impAcc[n] = accImp;
    }
}

// ---------------------------------------------------------------------------
// Kernel B: lane-per-point epilogue (round-10 winner), bf16 S input.
// W addresses wave-uniform -> s_load through K$; S per-lane row stream.
// ---------------------------------------------------------------------------
__global__ __launch_bounds__(256) void epilogue_g(
    const __hip_bfloat16* __restrict__ S, const float* __restrict__ impAcc,
    const float* __restrict__ Wc, const float* __restrict__ ba,
    const float* __restrict__ bb,
    float* __restrict__ outf, float* __restrict__ outimp, int nout)
{
    const int gtid   = blockIdx.x * 256 + threadIdx.x;
    const bool valid = (gtid < nout);
    const int n      = valid ? gtid : (nout - 1);

    const unsigned short* Sp =
        reinterpret_cast<const unsigned short*>(S + (size_t)n * SPP);

    float acc[COUT];
#pragma unroll
    for (int j = 0; j < COUT; ++j) acc[j] = 0.f;

    for (int t = 0; t < KCC; t += 8) {
        uint4 ua = *reinterpret_cast<const uint4*>(Sp + t);
        uint4 ub = *reinterpret_cast<const uint4*>(Sp + KCC + t);
        unsigned int uaw[4] = {ua.x, ua.y, ua.z, ua.w};
        unsigned int ubw[4] = {ub.x, ub.y, ub.z, ub.w};
        float sav[8], sbv[8];
#pragma unroll
        for (int p = 0; p < 4; ++p) {
            sav[2 * p]     = __uint_as_float(uaw[p] << 16);
            sav[2 * p + 1] = __uint_as_float(uaw[p] & 0xffff0000u);
            sbv[2 * p]     = __uint_as_float(ubw[p] << 16);
            sbv[2 * p + 1] = __uint_as_float(ubw[p] & 0xffff0000u);
        }
#pragma unroll
        for (int u = 0; u < 8; ++u) {
            const float* w = Wc + (t + u) * COUT;   // wave-uniform -> s_load
#pragma unroll
            for (int j = 0; j < CA; ++j) acc[j] = fmaf(sav[u], w[j], acc[j]);
#pragma unroll
            for (int j = 0; j < CB; ++j)
                acc[CA + j] = fmaf(sbv[u], w[CA + j], acc[CA + j]);
        }
    }

    float impTot = impAcc[n];
    float denom  = impTot > 0.f ? impTot : 1.f;

    if (valid) {
        float res[COUT];
#pragma unroll
        for (int j = 0; j < CA; ++j) res[j] = fmaxf(acc[j] + ba[j], 0.f);
#pragma unroll
        for (int j = 0; j < CB; ++j)
            res[CA + j] = fmaxf(acc[CA + j] / denom + bb[j], 0.f);
        float4* op = reinterpret_cast<float4*>(outf + (size_t)n * COUT);
#pragma unroll
        for (int j4 = 0; j4 < 8; ++j4)
            op[j4] = make_float4(res[4 * j4], res[4 * j4 + 1],
                                 res[4 * j4 + 2], res[4 * j4 + 3]);
        outimp[n] = impTot;
    }
}

// ===========================================================================
// Fallback (round-6 fused kernel) if ws can't hold the scratch.
// ===========================================================================
static constexpr int WSTR = KC * CIN + 4;
static constexpr int PPB = 16;
static constexpr int TPB = 512;
static constexpr int NHW = TPB / 32;

__global__ void build_rowptr_fb(const int* __restrict__ oidx, int* __restrict__ rp,
                                int E, int nout) {
    int e = blockIdx.x * blockDim.x + threadIdx.x;
    if (e >= E) return;
    int cur  = oidx[e];
    int prev = (e == 0) ? -1 : oidx[e - 1];
    for (int id = prev + 1; id <= cur; ++id) rp[id] = e;
    if (e == E - 1) {
        for (int id = cur + 1; id <= nout; ++id) rp[id] = E;
    }
}

__global__ void pack_weights_fkc(const float* __restrict__ Wa,
                                 const float* __restrict__ Wb,
                                 float* __restrict__ Wt) {
    int t = blockIdx.x * blockDim.x + threadIdx.x;
    if (t >= COUT * KC * CIN) return;
    int f = t / (KC * CIN);
    int r = t % (KC * CIN);
    Wt[t] = (f < CA) ? Wa[r * CA + f] : Wb[r * CB + (f - CA)];
}

__global__ __launch_bounds__(TPB) void fused_block(
    const float* __restrict__ feats, const float* __restrict__ importance,
    const float* __restrict__ Wt, const float* __restrict__ ba,
    const float* __restrict__ bb,
    const int* __restrict__ nidx, const int* __restrict__ nkidx,
    const int* __restrict__ noidx, const int* __restrict__ rp,
    float* __restrict__ outf, float* __restrict__ outimp, int nout)
{
    __shared__ __align__(16) float sW[COUT * WSTR];
    __shared__ __align__(16) float sS[PPB][2][KC * CIN];
    __shared__ float sImp[PPB];

    const int tid = threadIdx.x;
    const int hw  = tid >> 5;
    const int c   = tid & 31;
    const int p0  = blockIdx.x * PPB;

    {
        float* pS = &sS[0][0][0];
        for (int i = tid; i < PPB * 2 * KC * CIN; i += TPB) pS[i] = 0.f;
        for (int i = tid; i < COUT * KC * CIN; i += TPB) {
            int f = i / (KC * CIN);
            int r = i % (KC * CIN);
            sW[f * WSTR + r] = Wt[i];
        }
        if (tid < PPB) sImp[tid] = 0.f;
    }
    __syncthreads();

    const int pend   = (p0 + PPB < nout) ? (p0 + PPB) : nout;
    const int estart = rp[p0];
    const int eend   = rp[pend];
    const int cnt    = eend - estart;
    const int per    = (cnt + NHW - 1) / NHW;
    int a = estart + hw * per;
    int b = a + per; if (b > eend) b = eend;

    float* S0 = &sS[0][0][0];
    for (int e = a; e < b; ++e) {
        int   n0 = noidx[e], i0 = nidx[e], q0 = nkidx[e];
        float m0 = importance[i0];
        float f0 = feats[(size_t)i0 * CIN + c];
        float* bp = S0 + (n0 - p0) * (2 * KC * CIN) + q0 * CIN + c;
        atomicAdd(bp, f0);
        atomicAdd(bp + KC * CIN, f0 * m0);
        if (c == 0) atomicAdd(&sImp[n0 - p0], m0);
    }
    __syncthreads();

    const int wave = tid >> 6;
    const int lane = tid & 63;
    const int f    = lane & 31;
    const int h    = lane >> 5;
#pragma unroll
    for (int rep = 0; rep < 2; ++rep) {
        const int slot = wave * 2 + rep;
        const int n    = p0 + slot;
        if (n >= nout) break;
        float impTot = sImp[slot];
        float denom  = impTot > 0.f ? impTot : 1.f;
        const float* Sbase = &sS[slot][(f < CA) ? 0 : 1][0];
        const float* Wbase = sW + f * WSTR;
        float acc = 0.f;
#pragma unroll
        for (int k = 0; k < KC; ++k) {
            int off = k * CIN + h * 16;
#pragma unroll
            for (int j = 0; j < 16; ++j) acc = fmaf(Sbase[off + j], Wbase[off + j], acc);
        }
        float tot = acc + __shfl_xor(acc, 32, 64);
        if (h == 0) {
            float res = (f < CA) ? (tot + ba[f]) : (tot / denom + bb[f - CA]);
            outf[(size_t)n * COUT + f] = fmaxf(res, 0.f);
        }
        if (lane == 0) outimp[n] = impTot;
    }
}

// ---------------------------------------------------------------------------
extern "C" void kernel_launch(void* const* d_in, const int* in_sizes, int n_in,
                              void* d_out, int out_size, void* d_ws, size_t ws_size,
                              hipStream_t stream) {
    const float* feats      = (const float*)d_in[0];
    const float* importance = (const float*)d_in[1];
    const float* Wa         = (const float*)d_in[2];
    const float* ba         = (const float*)d_in[3];
    const float* Wb         = (const float*)d_in[4];
    const float* bb         = (const float*)d_in[5];
    const int*   nidx       = (const int*)d_in[6];
    const int*   nkidx      = (const int*)d_in[7];
    const int*   noidx      = (const int*)d_in[8];

    const int E    = in_sizes[6];
    const int nout = out_size / (COUT + 1);

    float* outf   = (float*)d_out;
    float* outimp = outf + (size_t)nout * COUT;

    // ws: S bf16 [nout*576] | impAcc [nout] | Wc [288*32] | rp [nout+1] | imp_e [E]
    const size_t off_imp = ((size_t)nout * SPP * sizeof(__hip_bfloat16) + 255) & ~(size_t)255;
    const size_t off_wc  = (off_imp + (size_t)nout * sizeof(float) + 255) & ~(size_t)255;
    const size_t off_rp  = (off_wc + (size_t)KCC * COUT * sizeof(float) + 255) & ~(size_t)255;
    const size_t off_ie  = (off_rp + (size_t)(nout + 1) * sizeof(int) + 255) & ~(size_t)255;
    const size_t need    = off_ie + (size_t)E * sizeof(float);

    if (ws_size >= need) {
        __hip_bfloat16* S = (__hip_bfloat16*)d_ws;
        float* impAcc = (float*)((char*)d_ws + off_imp);
        float* Wc     = (float*)((char*)d_ws + off_wc);
        int*   rp     = (int*)((char*)d_ws + off_rp);
        float* imp_e  = (float*)((char*)d_ws + off_ie);

        prep<<<(E + 255) / 256, 256, 0, stream>>>(
            noidx, nidx, importance, Wa, Wb, rp, imp_e, Wc, E, nout);
        accum_u<<<2048, 256, 0, stream>>>(
            feats, imp_e, nidx, nkidx, rp, S, impAcc, nout);
        epilogue_g<<<(nout + 255) / 256, 256, 0, stream>>>(
            S, impAcc, Wc, ba, bb, outf, outimp, nout);
    } else {
        int*   rp = (int*)d_ws;
        size_t rp_bytes = ((size_t)(nout + 1) * sizeof(int) + 255) & ~(size_t)255;
        float* Wt = (float*)((char*)d_ws + rp_bytes);

        build_rowptr_fb<<<(E + 255) / 256, 256, 0, stream>>>(noidx, rp, E, nout);
        pack_weights_fkc<<<(COUT * KC * CIN + 255) / 256, 256, 0, stream>>>(Wa, Wb, Wt);
        fused_block<<<(nout + PPB - 1) / PPB, TPB, 0, stream>>>(
            feats, importance, Wt, ba, bb, nidx, nkidx, noidx, rp,
            outf, outimp, nout);
    }
}